// Round 4
// baseline (956.139 us; speedup 1.0000x reference)
//
#include <hip/hip_runtime.h>
#include <hip/hip_bf16.h>
#include <math.h>

#define B_    32
#define T_    32
#define L_    64
#define EMB_  256
#define HID_  512
#define G4_   2048   // 4*HID
#define V_    30000
#define NOBJ_ 91
#define NROWS 1024   // T_*B_
#define KTOT  608    // 512 (hid) + 96 (padded NOBJ)

#define NLEAF_    16u
#define BLK_PER_LEAF_ 16u

typedef short  s16x8 __attribute__((ext_vector_type(8)));
typedef float  f32x4 __attribute__((ext_vector_type(4)));
typedef unsigned short us8 __attribute__((ext_vector_type(8)));

__device__ __forceinline__ float sigmoidf_(float x) { return 1.0f / (1.0f + expf(-x)); }

// round-to-nearest-even fp32 -> bf16 bits
__device__ __forceinline__ unsigned short bf16rn(float x) {
  unsigned u = __float_as_uint(x);
  unsigned r = u + 0x7FFFu + ((u >> 16) & 1u);
  return (unsigned short)(r >> 16);
}
__device__ __forceinline__ float bf16tof(unsigned short h) {
  return __uint_as_float(((unsigned)h) << 16);
}

// async global->LDS, 16B per lane; LDS dest is wave-uniform base + lane*16.
__device__ __forceinline__ void gload_lds16(const unsigned short* g, unsigned short* l) {
  __builtin_amdgcn_global_load_lds(
      (const __attribute__((address_space(1))) unsigned int*)g,
      (__attribute__((address_space(3))) unsigned int*)l, 16, 0, 0);
}

// Fence-free tree grid barrier (round-1 win; unchanged). Monotonic counters,
// RELAXED agent-scope atomics -> no buffer_wbl2/buffer_inv storm.
__device__ __forceinline__ void grid_barrier_tree(unsigned* bar, unsigned t) {
  __syncthreads();
  if (threadIdx.x == 0) {
    const unsigned target = t + 1u;
    asm volatile("s_waitcnt vmcnt(0)" ::: "memory");
    unsigned* lc = bar + (blockIdx.x & (NLEAF_ - 1u)) * 16u;
    unsigned a = __hip_atomic_fetch_add(lc, 1u, __ATOMIC_RELAXED, __HIP_MEMORY_SCOPE_AGENT) + 1u;
    if (a == target * BLK_PER_LEAF_) {
      unsigned r = __hip_atomic_fetch_add(bar + 256, 1u, __ATOMIC_RELAXED, __HIP_MEMORY_SCOPE_AGENT) + 1u;
      if (r == target * NLEAF_) {
        __hip_atomic_store(bar + 272, target, __ATOMIC_RELAXED, __HIP_MEMORY_SCOPE_AGENT);
      }
    }
    unsigned cur;
    do {
      __builtin_amdgcn_s_sleep(1);
      cur = __hip_atomic_load(bar + 272, __ATOMIC_RELAXED, __HIP_MEMORY_SCOPE_AGENT);
    } while (cur < target);
  }
  __syncthreads();
}

// ---------------- kernel 1: gather embeddings, time-major X[n][256], n = t*32+b
__global__ void k_gather(const float* __restrict__ features,
                         const int*   __restrict__ captions,
                         const float* __restrict__ embed_W,
                         float* __restrict__ X) {
  int n = blockIdx.x, e = threadIdx.x;          // 1024 blocks x 256 threads
  int t = n >> 5, b = n & 31;
  float v;
  if (t == 0) v = features[b * EMB_ + e];
  else        v = embed_W[captions[b * T_ + (t - 1)] * EMB_ + e];
  X[n * EMB_ + e] = v;
}

// ---------------- generic tiled f32 GEMM: C[M,N] = A[M,K] @ B[N,K]^T (+bias1[n]+bias2[n])
__global__ void k_gemm_bt(const float* __restrict__ A, const float* __restrict__ Bm,
                          const float* __restrict__ bias1, const float* __restrict__ bias2,
                          float* __restrict__ C, int M, int N, int K) {
  __shared__ float As[32][68];
  __shared__ float Bs[32][68];
  int tid = threadIdx.x;
  int tx = tid & 15, ty = tid >> 4;
  int n0 = blockIdx.x * 64, m0 = blockIdx.y * 64;
  float acc[4][4] = {};
  for (int k0 = 0; k0 < K; k0 += 32) {
    #pragma unroll
    for (int rep = 0; rep < 2; ++rep) {
      int idx = rep * 256 + tid;          // [0,512)
      int row = idx >> 3, kq = (idx & 7) * 4;
      float4 a4 = *(const float4*)&A[(m0 + row) * K + k0 + kq];
      As[kq + 0][row] = a4.x; As[kq + 1][row] = a4.y;
      As[kq + 2][row] = a4.z; As[kq + 3][row] = a4.w;
      float4 b4 = *(const float4*)&Bm[(n0 + row) * K + k0 + kq];
      Bs[kq + 0][row] = b4.x; Bs[kq + 1][row] = b4.y;
      Bs[kq + 2][row] = b4.z; Bs[kq + 3][row] = b4.w;
    }
    __syncthreads();
    #pragma unroll
    for (int k = 0; k < 32; ++k) {
      float4 a4 = *(const float4*)&As[k][ty * 4];
      float4 b4 = *(const float4*)&Bs[k][tx * 4];
      float av[4] = {a4.x, a4.y, a4.z, a4.w};
      float bv[4] = {b4.x, b4.y, b4.z, b4.w};
      #pragma unroll
      for (int i = 0; i < 4; ++i)
        #pragma unroll
        for (int j = 0; j < 4; ++j)
          acc[i][j] += av[i] * bv[j];
    }
    __syncthreads();
  }
  int nn = n0 + tx * 4;
  float bb[4] = {0.f, 0.f, 0.f, 0.f};
  if (bias1) {
    #pragma unroll
    for (int j = 0; j < 4; ++j) bb[j] += bias1[nn + j];
  }
  if (bias2) {
    #pragma unroll
    for (int j = 0; j < 4; ++j) bb[j] += bias2[nn + j];
  }
  #pragma unroll
  for (int i = 0; i < 4; ++i) {
    int m = m0 + ty * 4 + i;
    float4 o;
    o.x = acc[i][0] + bb[0]; o.y = acc[i][1] + bb[1];
    o.z = acc[i][2] + bb[2]; o.w = acc[i][3] + bb[3];
    *(float4*)&C[m * N + nn] = o;
  }
}

// ---------------- split linear_W [30000][512] -> B_hi/B_lo rows (stride 608, cols 0..511)
__global__ void k_split_lw(const float* __restrict__ in, unsigned short* __restrict__ hi,
                           unsigned short* __restrict__ lo) {
  const int n4 = V_ * 512 / 4;
  int i = blockIdx.x * 256 + threadIdx.x;
  int stride = gridDim.x * 256;
  for (; i < n4; i += stride) {
    int row = i >> 7, c = (i & 127) << 2;
    float4 v = ((const float4*)in)[i];
    ushort4 h, l;
    h.x = bf16rn(v.x); l.x = bf16rn(v.x - bf16tof(h.x));
    h.y = bf16rn(v.y); l.y = bf16rn(v.y - bf16tof(h.y));
    h.z = bf16rn(v.z); l.z = bf16rn(v.z - bf16tof(h.z));
    h.w = bf16rn(v.w); l.w = bf16rn(v.w - bf16tof(h.w));
    size_t d = (size_t)row * KTOT + c;
    *(ushort4*)(hi + d) = h;
    *(ushort4*)(lo + d) = l;
  }
}

// ---------------- split pg-scaled hs [1024][512] -> A_hi/A_lo (stride 608, cols 0..511)
__global__ void k_split_hs(const float* __restrict__ in, const float* __restrict__ pgen,
                           unsigned short* __restrict__ hi, unsigned short* __restrict__ lo) {
  int i = blockIdx.x * 256 + threadIdx.x;   // 512 blocks x 256 = exactly 131072 float4
  int row = i >> 7, c = (i & 127) << 2;
  float pg = pgen[row];
  float4 v = ((const float4*)in)[i];
  v.x *= pg; v.y *= pg; v.z *= pg; v.w *= pg;
  ushort4 h, l;
  h.x = bf16rn(v.x); l.x = bf16rn(v.x - bf16tof(h.x));
  h.y = bf16rn(v.y); l.y = bf16rn(v.y - bf16tof(h.y));
  h.z = bf16rn(v.z); l.z = bf16rn(v.z - bf16tof(h.z));
  h.w = bf16rn(v.w); l.w = bf16rn(v.w - bf16tof(h.w));
  size_t d = (size_t)row * KTOT + c;
  *(ushort4*)(hi + d) = h;
  *(ushort4*)(lo + d) = l;
}

// ---------------- transpose converter -> B_hi/B_lo cols 512..607 (o >= 91 zeroed)
__global__ void k_convt(const float* __restrict__ conv, unsigned short* __restrict__ cvh,
                        unsigned short* __restrict__ cvl) {
  __shared__ float t[NOBJ_][65];
  int tid = threadIdx.x;
  int v0 = blockIdx.x * 64;
  {
    int c = tid & 63, og = tid >> 6;
    for (int o = og; o < NOBJ_; o += 4) {
      int col = v0 + c;
      t[o][c] = (col < V_) ? conv[(size_t)o * V_ + col] : 0.f;
    }
  }
  __syncthreads();
  int row = tid >> 2, part = tid & 3;
  int gr = v0 + row;
  if (gr < V_) {
    unsigned short hb[24], lb[24];
    #pragma unroll
    for (int j = 0; j < 24; ++j) {
      int o = part * 24 + j;
      float x = (o < NOBJ_) ? t[o][row] : 0.f;
      unsigned short h = bf16rn(x);
      hb[j] = h;
      lb[j] = bf16rn(x - bf16tof(h));
    }
    size_t base = (size_t)gr * KTOT + 512 + part * 24;
    #pragma unroll
    for (int k = 0; k < 3; ++k) {
      *(us8*)(cvh + base + k * 8) = *(us8*)&hb[k * 8];
      *(us8*)(cvl + base + k * 8) = *(us8*)&lb[k * 8];
    }
  }
}

// ---------------- cooperative persistent LSTM (round-1 structure, unchanged)
__global__ __launch_bounds__(256) void k_lstm_coop(
    const float* __restrict__ Xg,    // [1024][2048] input gates (time-major)
    const float* __restrict__ W_hh,  // [2048][512]
    float* __restrict__ hTbuf,       // [2][512][32]
    float* __restrict__ hs,          // [1024][512]
    unsigned* __restrict__ bar) {
  __shared__ float wt_s[512 * 8];
  __shared__ float gredw[4 * 8 * 32];
  const int m = blockIdx.x;
  const int j0 = 2 * m;
  const int tid = threadIdx.x;
  const int kc = tid >> 4;
  const int rg = (tid >> 3) & 1;
  const int bg = tid & 7;
  const int jj = tid >> 5, bb = tid & 31;

  {
    int q = tid >> 5, lane = tid & 31;
    const float* src = W_hh + (size_t)((q >> 1) * 512 + j0 + (q & 1)) * HID_;
    for (int kk = 0; kk < 16; ++kk) {
      int k = kk * 32 + lane;
      wt_s[k * 8 + q] = src[k];
    }
  }
  __syncthreads();

  float c = 0.0f;
  for (int t = 0; t < T_; ++t) {
    const float* hTcur = hTbuf + (t & 1) * (HID_ * B_);
    float* hTnext      = hTbuf + ((t + 1) & 1) * (HID_ * B_);
    float xg0 = 0.f, xg1 = 0.f, xg2 = 0.f, xg3 = 0.f;
    if (tid < 64) {
      const float* xp = Xg + (size_t)(t * B_ + bb) * G4_ + j0 + jj;
      xg0 = xp[0]; xg1 = xp[512]; xg2 = xp[1024]; xg3 = xp[1536];
    }
    float acc[4][4] = {};
    if (t > 0) {
      #pragma unroll 4
      for (int kk = 0; kk < 32; ++kk) {
        const unsigned long long* hp =
            (const unsigned long long*)&hTcur[kk * 512 + kc * 32 + 4 * bg];
        unsigned long long u0 = __hip_atomic_load(hp,     __ATOMIC_RELAXED, __HIP_MEMORY_SCOPE_AGENT);
        unsigned long long u1 = __hip_atomic_load(hp + 1, __ATOMIC_RELAXED, __HIP_MEMORY_SCOPE_AGENT);
        union { unsigned long long u; float f[2]; } c0, c1;
        c0.u = u0; c1.u = u1;
        float hx = c0.f[0], hy = c0.f[1], hz = c1.f[0], hw = c1.f[1];
        float4 w4 = *(const float4*)&wt_s[(kk * 16 + kc) * 8 + 4 * rg];
        acc[0][0] += w4.x * hx; acc[0][1] += w4.x * hy; acc[0][2] += w4.x * hz; acc[0][3] += w4.x * hw;
        acc[1][0] += w4.y * hx; acc[1][1] += w4.y * hy; acc[1][2] += w4.y * hz; acc[1][3] += w4.y * hw;
        acc[2][0] += w4.z * hx; acc[2][1] += w4.z * hy; acc[2][2] += w4.z * hz; acc[2][3] += w4.z * hw;
        acc[3][0] += w4.w * hx; acc[3][1] += w4.w * hy; acc[3][2] += w4.w * hz; acc[3][3] += w4.w * hw;
      }
    }
    #pragma unroll
    for (int j = 0; j < 4; ++j)
      #pragma unroll
      for (int i = 0; i < 4; ++i) {
        acc[j][i] += __shfl_xor(acc[j][i], 16);
        acc[j][i] += __shfl_xor(acc[j][i], 32);
      }
    if ((tid & 63) < 16) {
      int w = tid >> 6;
      #pragma unroll
      for (int j = 0; j < 4; ++j) {
        float4 v; v.x = acc[j][0]; v.y = acc[j][1]; v.z = acc[j][2]; v.w = acc[j][3];
        *(float4*)&gredw[w * 256 + (rg * 4 + j) * 32 + bg * 4] = v;
      }
    }
    __syncthreads();
    if (tid < 64) {
      float s0 = xg0, s1 = xg1, s2 = xg2, s3 = xg3;
      #pragma unroll
      for (int w = 0; w < 4; ++w) {
        s0 += gredw[w * 256 + (0 * 2 + jj) * 32 + bb];
        s1 += gredw[w * 256 + (1 * 2 + jj) * 32 + bb];
        s2 += gredw[w * 256 + (2 * 2 + jj) * 32 + bb];
        s3 += gredw[w * 256 + (3 * 2 + jj) * 32 + bb];
      }
      float gi = sigmoidf_(s0), gf = sigmoidf_(s1);
      float gg = tanhf(s2),     go = sigmoidf_(s3);
      c = gf * c + gi * gg;
      float h = go * tanhf(c);
      __hip_atomic_store(&hTnext[(j0 + jj) * B_ + bb], h,
                         __ATOMIC_RELAXED, __HIP_MEMORY_SCOPE_AGENT);
      hs[(size_t)(t * B_ + bb) * HID_ + j0 + jj] = h;
    }
    if (t + 1 < T_) grid_barrier_tree(bar, (unsigned)t);
  }
}

// ---------------- attention; emits pgen and (1-pg)-scaled alpha into A cols 512..607
__global__ void k_attn(const float* __restrict__ hs, const float* __restrict__ q_ws,
                       const float* __restrict__ enc_out, const int* __restrict__ enc_in,
                       const float* __restrict__ pge_W, const float* __restrict__ pge_b,
                       const float* __restrict__ pgd_W, const float* __restrict__ pgd_b,
                       unsigned short* __restrict__ Ah, unsigned short* __restrict__ Al,
                       float* __restrict__ pgen) {
  __shared__ float h_s[HID_], q_s[EMB_], aw_s[L_], al_s[96], red_s[256];
  __shared__ float pg_sh;
  int n = blockIdx.x, tid = threadIdx.x;   // 1024 blocks x 256 threads
  int b = n & 31;
  h_s[tid]       = hs[n * HID_ + tid];
  h_s[tid + 256] = hs[n * HID_ + 256 + tid];
  q_s[tid]       = q_ws[n * EMB_ + tid];
  if (tid < 96) al_s[tid] = 0.0f;
  __syncthreads();
  {
    int l = tid >> 2, part = tid & 3;
    const float* er = enc_out + (size_t)(b * L_ + l) * EMB_ + part * 64;
    const float* qp = q_s + part * 64;
    float acc = 0.f;
    #pragma unroll 8
    for (int i = 0; i < 64; ++i) acc += qp[i] * er[i];
    red_s[tid] = acc;
  }
  __syncthreads();
  if (tid < 64) {
    float s = red_s[tid * 4] + red_s[tid * 4 + 1] + red_s[tid * 4 + 2] + red_s[tid * 4 + 3];
    if (enc_in[b * L_ + tid] == 0) s = -1e30f;
    float mx = s;
    for (int off = 32; off >= 1; off >>= 1) mx = fmaxf(mx, __shfl_xor(mx, off));
    float e = expf(s - mx);
    float sum = e;
    for (int off = 32; off >= 1; off >>= 1) sum += __shfl_xor(sum, off);
    aw_s[tid] = e / sum;
  }
  __syncthreads();
  float cacc = 0.f;
  for (int l2 = 0; l2 < L_; ++l2)
    cacc += aw_s[l2] * enc_out[(size_t)(b * L_ + l2) * EMB_ + tid];
  red_s[tid] = cacc * pge_W[tid] + h_s[tid] * pgd_W[tid] + h_s[tid + 256] * pgd_W[tid + 256];
  __syncthreads();
  for (int s2 = 128; s2 >= 1; s2 >>= 1) {
    if (tid < s2) red_s[tid] += red_s[tid + s2];
    __syncthreads();
  }
  if (tid == 0) {
    float p = 1.0f / (1.0f + expf(-(red_s[0] + pge_b[0] + pgd_b[0])));
    pgen[n] = p;
    pg_sh = p;
  }
  if (tid < 64) atomicAdd(&al_s[enc_in[b * L_ + tid]], aw_s[tid]);
  __syncthreads();
  if (tid < 96) {
    float a = al_s[tid] * (1.0f - pg_sh);
    unsigned short h = bf16rn(a);
    Ah[(size_t)n * KTOT + 512 + tid] = h;
    Al[(size_t)n * KTOT + 512 + tid] = bf16rn(a - bf16tof(h));
  }
}

// ---------------- fused output GEMM (m97 structure, split-bf16 3-term):
// out[n][v] = sum_k A[n][k]*B[v][k] + pg[n]*linb[v],  A = [pg*hs | (1-pg)*alpha], K=608.
// 128x128 tile, BK=32, 4 waves (2x2), wave tile 64x64 (4x4 16x16x32 MFMA tiles).
// LDS granule-major [g][row][8 bf16]: wave-linear gload_lds writes AND uniform
// ds_read_b128 frag reads. XCD-chunked swizzle: the 8 row-blocks of one B
// column-slice stay on one XCD -> B fetched once into that XCD's L2.
__global__ __launch_bounds__(256) void k_out_gemm(
    const unsigned short* __restrict__ Ahg, const unsigned short* __restrict__ Alg,
    const unsigned short* __restrict__ Bhg, const unsigned short* __restrict__ Blg,
    const float* __restrict__ linb, const float* __restrict__ pgen,
    float* __restrict__ out) {
  __shared__ __align__(16) unsigned short SM[16384];   // Ah|Al|Bh|Bl, 4x8KB
  const int tid  = threadIdx.x;
  const int wave = tid >> 6, lane = tid & 63;
  const int l15  = lane & 15, l4 = lane >> 4;
  const int wm   = wave >> 1, wn = wave & 1;

  // XCD-chunked bijective swizzle over 8 x 235 = 1880 blocks
  int orig = blockIdx.x;
  int idw  = (orig & 7) * 235 + (orig >> 3);
  int mx   = idw & 7, ny = idw >> 3;
  const int m0 = mx * 128, n0 = ny * 128;

  // staging role: wave 0->Ah, 1->Al, 2->Bh, 3->Bl; 8 x 1KB instructions each.
  // sub s covers granule g=s>>1 (k-offset g*8), row-half h=s&1 (rows h*64+lane).
  const unsigned short* gmat = (wave == 0) ? Ahg : (wave == 1) ? Alg : (wave == 2) ? Bhg : Blg;
  const int rbase = (wave < 2) ? m0 : n0;
  const bool isB  = (wave >= 2);
  int srow[8], sg[8];
  #pragma unroll
  for (int sub = 0; sub < 8; ++sub) {
    int id = sub * 64 + lane;
    int g = id >> 7, r = id & 127;
    int row = rbase + r;
    if (isB && row > V_ - 1) row = V_ - 1;
    srow[sub] = row; sg[sub] = g;
  }

  f32x4 acc[4][4] = {};

  for (int ks = 0; ks < KTOT / 32; ++ks) {
    const int k0 = ks * 32;
    #pragma unroll
    for (int sub = 0; sub < 8; ++sub) {
      const unsigned short* src = gmat + (size_t)srow[sub] * KTOT + k0 + sg[sub] * 8;
      gload_lds16(src, &SM[wave * 4096 + sub * 512]);
    }
    __syncthreads();   // compiler drains vmcnt(0) before s_barrier -> staged data visible
    s16x8 aH[4], aL[4], bH[4], bL[4];
    #pragma unroll
    for (int mi = 0; mi < 4; ++mi) {
      int off = (l4 * 128 + wm * 64 + mi * 16 + l15) * 8;
      aH[mi] = *(const s16x8*)&SM[off];
      aL[mi] = *(const s16x8*)&SM[4096 + off];
    }
    #pragma unroll
    for (int ni = 0; ni < 4; ++ni) {
      int off = (l4 * 128 + wn * 64 + ni * 16 + l15) * 8;
      bH[ni] = *(const s16x8*)&SM[8192 + off];
      bL[ni] = *(const s16x8*)&SM[12288 + off];
    }
    #pragma unroll
    for (int mi = 0; mi < 4; ++mi)
      #pragma unroll
      for (int ni = 0; ni < 4; ++ni) {
        acc[mi][ni] = __builtin_amdgcn_mfma_f32_16x16x32_bf16(aH[mi], bH[ni], acc[mi][ni], 0, 0, 0);
        acc[mi][ni] = __builtin_amdgcn_mfma_f32_16x16x32_bf16(aH[mi], bL[ni], acc[mi][ni], 0, 0, 0);
        acc[mi][ni] = __builtin_amdgcn_mfma_f32_16x16x32_bf16(aL[mi], bH[ni], acc[mi][ni], 0, 0, 0);
      }
    __syncthreads();
  }

  // epilogue: D frag col = lane&15, row = 4*(lane>>4)+reg  [m89-verified]
  float lbv[4]; int colv[4];
  #pragma unroll
  for (int ni = 0; ni < 4; ++ni) {
    int col = n0 + wn * 64 + ni * 16 + l15;
    colv[ni] = col;
    lbv[ni] = linb[col < V_ ? col : V_ - 1];
  }
  #pragma unroll
  for (int mi = 0; mi < 4; ++mi) {
    #pragma unroll
    for (int rr = 0; rr < 4; ++rr) {
      int row = m0 + wm * 64 + mi * 16 + l4 * 4 + rr;
      float pg = pgen[row];
      #pragma unroll
      for (int ni = 0; ni < 4; ++ni) {
        if (colv[ni] < V_)
          out[(size_t)row * V_ + colv[ni]] = acc[mi][ni][rr] + pg * lbv[ni];
      }
    }
  }
}

extern "C" void kernel_launch(void* const* d_in, const int* in_sizes, int n_in,
                              void* d_out, int out_size, void* d_ws, size_t ws_size,
                              hipStream_t stream) {
  const float* features = (const float*)d_in[0];
  const int*   captions = (const int*)d_in[1];
  const int*   enc_in   = (const int*)d_in[3];
  const float* enc_out  = (const float*)d_in[4];
  const float* embed_W  = (const float*)d_in[5];
  const float* W_ih     = (const float*)d_in[6];
  const float* W_hh     = (const float*)d_in[7];
  const float* b_ih     = (const float*)d_in[8];
  const float* b_hh     = (const float*)d_in[9];
  const float* linear_W = (const float*)d_in[10];
  const float* linear_b = (const float*)d_in[11];
  const float* attn_W   = (const float*)d_in[12];
  const float* attn_b   = (const float*)d_in[13];
  const float* pge_W    = (const float*)d_in[14];
  const float* pge_b    = (const float*)d_in[15];
  const float* pgd_W    = (const float*)d_in[16];
  const float* pgd_b    = (const float*)d_in[17];
  const float* conv     = (const float*)d_in[18];
  float* out = (float*)d_out;

  float* ws   = (float*)d_ws;
  float* X    = ws;                  // 262144 f
  float* Xg   = X    + 262144;       // 2097152 f
  float* hTb  = Xg   + 2097152;      // 32768 f
  float* hsb  = hTb  + 32768;        // 524288 f
  float* qws  = hsb  + 524288;       // 262144 f
  float* pgn  = qws  + 262144;       // 1024 f
  unsigned* bar = (unsigned*)(pgn + 1024);            // 1024 u32 reserved
  unsigned short* Ahg = (unsigned short*)(bar + 1024);
  unsigned short* Alg = Ahg + (size_t)NROWS * KTOT;   // 622592 each
  unsigned short* Bhg = Alg + (size_t)NROWS * KTOT;
  unsigned short* Blg = Bhg + (size_t)V_ * KTOT;      // 18240000 each

  hipMemsetAsync(bar, 0, 1024 * sizeof(unsigned), stream);
  // weight preprocessing (no deps on LSTM)
  k_split_lw<<<2048, 256, 0, stream>>>(linear_W, Bhg, Blg);
  k_convt   <<<469, 256, 0, stream>>>(conv, Bhg, Blg);

  k_gather <<<1024, 256, 0, stream>>>(features, captions, embed_W, X);
  k_gemm_bt<<<dim3(32, 16), 256, 0, stream>>>(X, W_ih, b_ih, b_hh, Xg, NROWS, G4_, EMB_);
  {
    const float* Xg_c = Xg;
    const float* Whh_c = W_hh;
    float* hTb_p = hTb;
    float* hsb_p = hsb;
    unsigned* bar_p = bar;
    void* args[] = { (void*)&Xg_c, (void*)&Whh_c, (void*)&hTb_p, (void*)&hsb_p,
                     (void*)&bar_p };
    hipLaunchCooperativeKernel((const void*)k_lstm_coop, dim3(256), dim3(256),
                               args, 0, stream);
  }
  k_gemm_bt<<<dim3(4, 16), 256, 0, stream>>>(hsb, attn_W, attn_b, nullptr, qws, NROWS, EMB_, HID_);
  k_attn   <<<1024, 256, 0, stream>>>(hsb, qws, enc_out, enc_in, pge_W, pge_b, pgd_W, pgd_b,
                                      Ahg, Alg, pgn);
  k_split_hs<<<512, 256, 0, stream>>>(hsb, pgn, Ahg, Alg);
  k_out_gemm<<<1880, 256, 0, stream>>>(Ahg, Alg, Bhg, Blg, linear_b, pgn, out);
}

// Round 5
// 747.029 us; speedup vs baseline: 1.2799x; 1.2799x over previous
//
#include <hip/hip_runtime.h>
#include <hip/hip_bf16.h>
#include <math.h>

#define B_    32
#define T_    32
#define L_    64
#define EMB_  256
#define HID_  512
#define G4_   2048   // 4*HID
#define V_    30000
#define NOBJ_ 91
#define NROWS 1024   // T_*B_
#define KTOT  608    // 512 (hid) + 96 (padded NOBJ)

#define NLEAF_    16u
#define BLK_PER_LEAF_ 16u

typedef short  s16x8 __attribute__((ext_vector_type(8)));
typedef float  f32x4 __attribute__((ext_vector_type(4)));
typedef unsigned short us8 __attribute__((ext_vector_type(8)));

__device__ __forceinline__ float sigmoidf_(float x) { return 1.0f / (1.0f + expf(-x)); }

// round-to-nearest-even fp32 -> bf16 bits
__device__ __forceinline__ unsigned short bf16rn(float x) {
  unsigned u = __float_as_uint(x);
  unsigned r = u + 0x7FFFu + ((u >> 16) & 1u);
  return (unsigned short)(r >> 16);
}
__device__ __forceinline__ float bf16tof(unsigned short h) {
  return __uint_as_float(((unsigned)h) << 16);
}

// async global->LDS, 16B per lane; LDS dest is wave-uniform base + lane*16.
__device__ __forceinline__ void gload_lds16(const unsigned short* g, unsigned short* l) {
  __builtin_amdgcn_global_load_lds(
      (const __attribute__((address_space(1))) unsigned int*)g,
      (__attribute__((address_space(3))) unsigned int*)l, 16, 0, 0);
}

// Fence-free tree grid barrier (round-1 win; unchanged). Monotonic counters,
// RELAXED agent-scope atomics -> no buffer_wbl2/buffer_inv storm.
__device__ __forceinline__ void grid_barrier_tree(unsigned* bar, unsigned t) {
  __syncthreads();
  if (threadIdx.x == 0) {
    const unsigned target = t + 1u;
    asm volatile("s_waitcnt vmcnt(0)" ::: "memory");
    unsigned* lc = bar + (blockIdx.x & (NLEAF_ - 1u)) * 16u;
    unsigned a = __hip_atomic_fetch_add(lc, 1u, __ATOMIC_RELAXED, __HIP_MEMORY_SCOPE_AGENT) + 1u;
    if (a == target * BLK_PER_LEAF_) {
      unsigned r = __hip_atomic_fetch_add(bar + 256, 1u, __ATOMIC_RELAXED, __HIP_MEMORY_SCOPE_AGENT) + 1u;
      if (r == target * NLEAF_) {
        __hip_atomic_store(bar + 272, target, __ATOMIC_RELAXED, __HIP_MEMORY_SCOPE_AGENT);
      }
    }
    unsigned cur;
    do {
      __builtin_amdgcn_s_sleep(1);
      cur = __hip_atomic_load(bar + 272, __ATOMIC_RELAXED, __HIP_MEMORY_SCOPE_AGENT);
    } while (cur < target);
  }
  __syncthreads();
}

// ---------------- kernel 1: gather embeddings, time-major X[n][256], n = t*32+b
__global__ void k_gather(const float* __restrict__ features,
                         const int*   __restrict__ captions,
                         const float* __restrict__ embed_W,
                         float* __restrict__ X) {
  int n = blockIdx.x, e = threadIdx.x;          // 1024 blocks x 256 threads
  int t = n >> 5, b = n & 31;
  float v;
  if (t == 0) v = features[b * EMB_ + e];
  else        v = embed_W[captions[b * T_ + (t - 1)] * EMB_ + e];
  X[n * EMB_ + e] = v;
}

// ---------------- generic tiled f32 GEMM: C[M,N] = A[M,K] @ B[N,K]^T (+bias1[n]+bias2[n])
__global__ void k_gemm_bt(const float* __restrict__ A, const float* __restrict__ Bm,
                          const float* __restrict__ bias1, const float* __restrict__ bias2,
                          float* __restrict__ C, int M, int N, int K) {
  __shared__ float As[32][68];
  __shared__ float Bs[32][68];
  int tid = threadIdx.x;
  int tx = tid & 15, ty = tid >> 4;
  int n0 = blockIdx.x * 64, m0 = blockIdx.y * 64;
  float acc[4][4] = {};
  for (int k0 = 0; k0 < K; k0 += 32) {
    #pragma unroll
    for (int rep = 0; rep < 2; ++rep) {
      int idx = rep * 256 + tid;          // [0,512)
      int row = idx >> 3, kq = (idx & 7) * 4;
      float4 a4 = *(const float4*)&A[(m0 + row) * K + k0 + kq];
      As[kq + 0][row] = a4.x; As[kq + 1][row] = a4.y;
      As[kq + 2][row] = a4.z; As[kq + 3][row] = a4.w;
      float4 b4 = *(const float4*)&Bm[(n0 + row) * K + k0 + kq];
      Bs[kq + 0][row] = b4.x; Bs[kq + 1][row] = b4.y;
      Bs[kq + 2][row] = b4.z; Bs[kq + 3][row] = b4.w;
    }
    __syncthreads();
    #pragma unroll
    for (int k = 0; k < 32; ++k) {
      float4 a4 = *(const float4*)&As[k][ty * 4];
      float4 b4 = *(const float4*)&Bs[k][tx * 4];
      float av[4] = {a4.x, a4.y, a4.z, a4.w};
      float bv[4] = {b4.x, b4.y, b4.z, b4.w};
      #pragma unroll
      for (int i = 0; i < 4; ++i)
        #pragma unroll
        for (int j = 0; j < 4; ++j)
          acc[i][j] += av[i] * bv[j];
    }
    __syncthreads();
  }
  int nn = n0 + tx * 4;
  float bb[4] = {0.f, 0.f, 0.f, 0.f};
  if (bias1) {
    #pragma unroll
    for (int j = 0; j < 4; ++j) bb[j] += bias1[nn + j];
  }
  if (bias2) {
    #pragma unroll
    for (int j = 0; j < 4; ++j) bb[j] += bias2[nn + j];
  }
  #pragma unroll
  for (int i = 0; i < 4; ++i) {
    int m = m0 + ty * 4 + i;
    float4 o;
    o.x = acc[i][0] + bb[0]; o.y = acc[i][1] + bb[1];
    o.z = acc[i][2] + bb[2]; o.w = acc[i][3] + bb[3];
    *(float4*)&C[m * N + nn] = o;
  }
}

// ---------------- split linear_W [30000][512] -> B_hi/B_lo rows (stride 608, cols 0..511)
__global__ void k_split_lw(const float* __restrict__ in, unsigned short* __restrict__ hi,
                           unsigned short* __restrict__ lo) {
  const int n4 = V_ * 512 / 4;
  int i = blockIdx.x * 256 + threadIdx.x;
  int stride = gridDim.x * 256;
  for (; i < n4; i += stride) {
    int row = i >> 7, c = (i & 127) << 2;
    float4 v = ((const float4*)in)[i];
    ushort4 h, l;
    h.x = bf16rn(v.x); l.x = bf16rn(v.x - bf16tof(h.x));
    h.y = bf16rn(v.y); l.y = bf16rn(v.y - bf16tof(h.y));
    h.z = bf16rn(v.z); l.z = bf16rn(v.z - bf16tof(h.z));
    h.w = bf16rn(v.w); l.w = bf16rn(v.w - bf16tof(h.w));
    size_t d = (size_t)row * KTOT + c;
    *(ushort4*)(hi + d) = h;
    *(ushort4*)(lo + d) = l;
  }
}

// ---------------- split pg-scaled hs [1024][512] -> A_hi/A_lo (stride 608, cols 0..511)
__global__ void k_split_hs(const float* __restrict__ in, const float* __restrict__ pgen,
                           unsigned short* __restrict__ hi, unsigned short* __restrict__ lo) {
  int i = blockIdx.x * 256 + threadIdx.x;   // 512 blocks x 256 = exactly 131072 float4
  int row = i >> 7, c = (i & 127) << 2;
  float pg = pgen[row];
  float4 v = ((const float4*)in)[i];
  v.x *= pg; v.y *= pg; v.z *= pg; v.w *= pg;
  ushort4 h, l;
  h.x = bf16rn(v.x); l.x = bf16rn(v.x - bf16tof(h.x));
  h.y = bf16rn(v.y); l.y = bf16rn(v.y - bf16tof(h.y));
  h.z = bf16rn(v.z); l.z = bf16rn(v.z - bf16tof(h.z));
  h.w = bf16rn(v.w); l.w = bf16rn(v.w - bf16tof(h.w));
  size_t d = (size_t)row * KTOT + c;
  *(ushort4*)(hi + d) = h;
  *(ushort4*)(lo + d) = l;
}

// ---------------- transpose converter -> B_hi/B_lo cols 512..607 (o >= 91 zeroed)
__global__ void k_convt(const float* __restrict__ conv, unsigned short* __restrict__ cvh,
                        unsigned short* __restrict__ cvl) {
  __shared__ float t[NOBJ_][65];
  int tid = threadIdx.x;
  int v0 = blockIdx.x * 64;
  {
    int c = tid & 63, og = tid >> 6;
    for (int o = og; o < NOBJ_; o += 4) {
      int col = v0 + c;
      t[o][c] = (col < V_) ? conv[(size_t)o * V_ + col] : 0.f;
    }
  }
  __syncthreads();
  int row = tid >> 2, part = tid & 3;
  int gr = v0 + row;
  if (gr < V_) {
    unsigned short hb[24], lb[24];
    #pragma unroll
    for (int j = 0; j < 24; ++j) {
      int o = part * 24 + j;
      float x = (o < NOBJ_) ? t[o][row] : 0.f;
      unsigned short h = bf16rn(x);
      hb[j] = h;
      lb[j] = bf16rn(x - bf16tof(h));
    }
    size_t base = (size_t)gr * KTOT + 512 + part * 24;
    #pragma unroll
    for (int k = 0; k < 3; ++k) {
      *(us8*)(cvh + base + k * 8) = *(us8*)&hb[k * 8];
      *(us8*)(cvl + base + k * 8) = *(us8*)&lb[k * 8];
    }
  }
}

// ---------------- cooperative persistent LSTM (round-1 structure, unchanged)
__global__ __launch_bounds__(256) void k_lstm_coop(
    const float* __restrict__ Xg,    // [1024][2048] input gates (time-major)
    const float* __restrict__ W_hh,  // [2048][512]
    float* __restrict__ hTbuf,       // [2][512][32]
    float* __restrict__ hs,          // [1024][512]
    unsigned* __restrict__ bar) {
  __shared__ float wt_s[512 * 8];
  __shared__ float gredw[4 * 8 * 32];
  const int m = blockIdx.x;
  const int j0 = 2 * m;
  const int tid = threadIdx.x;
  const int kc = tid >> 4;
  const int rg = (tid >> 3) & 1;
  const int bg = tid & 7;
  const int jj = tid >> 5, bb = tid & 31;

  {
    int q = tid >> 5, lane = tid & 31;
    const float* src = W_hh + (size_t)((q >> 1) * 512 + j0 + (q & 1)) * HID_;
    for (int kk = 0; kk < 16; ++kk) {
      int k = kk * 32 + lane;
      wt_s[k * 8 + q] = src[k];
    }
  }
  __syncthreads();

  float c = 0.0f;
  for (int t = 0; t < T_; ++t) {
    const float* hTcur = hTbuf + (t & 1) * (HID_ * B_);
    float* hTnext      = hTbuf + ((t + 1) & 1) * (HID_ * B_);
    float xg0 = 0.f, xg1 = 0.f, xg2 = 0.f, xg3 = 0.f;
    if (tid < 64) {
      const float* xp = Xg + (size_t)(t * B_ + bb) * G4_ + j0 + jj;
      xg0 = xp[0]; xg1 = xp[512]; xg2 = xp[1024]; xg3 = xp[1536];
    }
    float acc[4][4] = {};
    if (t > 0) {
      #pragma unroll 4
      for (int kk = 0; kk < 32; ++kk) {
        const unsigned long long* hp =
            (const unsigned long long*)&hTcur[kk * 512 + kc * 32 + 4 * bg];
        unsigned long long u0 = __hip_atomic_load(hp,     __ATOMIC_RELAXED, __HIP_MEMORY_SCOPE_AGENT);
        unsigned long long u1 = __hip_atomic_load(hp + 1, __ATOMIC_RELAXED, __HIP_MEMORY_SCOPE_AGENT);
        union { unsigned long long u; float f[2]; } c0, c1;
        c0.u = u0; c1.u = u1;
        float hx = c0.f[0], hy = c0.f[1], hz = c1.f[0], hw = c1.f[1];
        float4 w4 = *(const float4*)&wt_s[(kk * 16 + kc) * 8 + 4 * rg];
        acc[0][0] += w4.x * hx; acc[0][1] += w4.x * hy; acc[0][2] += w4.x * hz; acc[0][3] += w4.x * hw;
        acc[1][0] += w4.y * hx; acc[1][1] += w4.y * hy; acc[1][2] += w4.y * hz; acc[1][3] += w4.y * hw;
        acc[2][0] += w4.z * hx; acc[2][1] += w4.z * hy; acc[2][2] += w4.z * hz; acc[2][3] += w4.z * hw;
        acc[3][0] += w4.w * hx; acc[3][1] += w4.w * hy; acc[3][2] += w4.w * hz; acc[3][3] += w4.w * hw;
      }
    }
    #pragma unroll
    for (int j = 0; j < 4; ++j)
      #pragma unroll
      for (int i = 0; i < 4; ++i) {
        acc[j][i] += __shfl_xor(acc[j][i], 16);
        acc[j][i] += __shfl_xor(acc[j][i], 32);
      }
    if ((tid & 63) < 16) {
      int w = tid >> 6;
      #pragma unroll
      for (int j = 0; j < 4; ++j) {
        float4 v; v.x = acc[j][0]; v.y = acc[j][1]; v.z = acc[j][2]; v.w = acc[j][3];
        *(float4*)&gredw[w * 256 + (rg * 4 + j) * 32 + bg * 4] = v;
      }
    }
    __syncthreads();
    if (tid < 64) {
      float s0 = xg0, s1 = xg1, s2 = xg2, s3 = xg3;
      #pragma unroll
      for (int w = 0; w < 4; ++w) {
        s0 += gredw[w * 256 + (0 * 2 + jj) * 32 + bb];
        s1 += gredw[w * 256 + (1 * 2 + jj) * 32 + bb];
        s2 += gredw[w * 256 + (2 * 2 + jj) * 32 + bb];
        s3 += gredw[w * 256 + (3 * 2 + jj) * 32 + bb];
      }
      float gi = sigmoidf_(s0), gf = sigmoidf_(s1);
      float gg = tanhf(s2),     go = sigmoidf_(s3);
      c = gf * c + gi * gg;
      float h = go * tanhf(c);
      __hip_atomic_store(&hTnext[(j0 + jj) * B_ + bb], h,
                         __ATOMIC_RELAXED, __HIP_MEMORY_SCOPE_AGENT);
      hs[(size_t)(t * B_ + bb) * HID_ + j0 + jj] = h;
    }
    if (t + 1 < T_) grid_barrier_tree(bar, (unsigned)t);
  }
}

// ---------------- attention; emits pgen and (1-pg)-scaled alpha into A cols 512..607
__global__ void k_attn(const float* __restrict__ hs, const float* __restrict__ q_ws,
                       const float* __restrict__ enc_out, const int* __restrict__ enc_in,
                       const float* __restrict__ pge_W, const float* __restrict__ pge_b,
                       const float* __restrict__ pgd_W, const float* __restrict__ pgd_b,
                       unsigned short* __restrict__ Ah, unsigned short* __restrict__ Al,
                       float* __restrict__ pgen) {
  __shared__ float h_s[HID_], q_s[EMB_], aw_s[L_], al_s[96], red_s[256];
  __shared__ float pg_sh;
  int n = blockIdx.x, tid = threadIdx.x;   // 1024 blocks x 256 threads
  int b = n & 31;
  h_s[tid]       = hs[n * HID_ + tid];
  h_s[tid + 256] = hs[n * HID_ + 256 + tid];
  q_s[tid]       = q_ws[n * EMB_ + tid];
  if (tid < 96) al_s[tid] = 0.0f;
  __syncthreads();
  {
    int l = tid >> 2, part = tid & 3;
    const float* er = enc_out + (size_t)(b * L_ + l) * EMB_ + part * 64;
    const float* qp = q_s + part * 64;
    float acc = 0.f;
    #pragma unroll 8
    for (int i = 0; i < 64; ++i) acc += qp[i] * er[i];
    red_s[tid] = acc;
  }
  __syncthreads();
  if (tid < 64) {
    float s = red_s[tid * 4] + red_s[tid * 4 + 1] + red_s[tid * 4 + 2] + red_s[tid * 4 + 3];
    if (enc_in[b * L_ + tid] == 0) s = -1e30f;
    float mx = s;
    for (int off = 32; off >= 1; off >>= 1) mx = fmaxf(mx, __shfl_xor(mx, off));
    float e = expf(s - mx);
    float sum = e;
    for (int off = 32; off >= 1; off >>= 1) sum += __shfl_xor(sum, off);
    aw_s[tid] = e / sum;
  }
  __syncthreads();
  float cacc = 0.f;
  for (int l2 = 0; l2 < L_; ++l2)
    cacc += aw_s[l2] * enc_out[(size_t)(b * L_ + l2) * EMB_ + tid];
  red_s[tid] = cacc * pge_W[tid] + h_s[tid] * pgd_W[tid] + h_s[tid + 256] * pgd_W[tid + 256];
  __syncthreads();
  for (int s2 = 128; s2 >= 1; s2 >>= 1) {
    if (tid < s2) red_s[tid] += red_s[tid + s2];
    __syncthreads();
  }
  if (tid == 0) {
    float p = 1.0f / (1.0f + expf(-(red_s[0] + pge_b[0] + pgd_b[0])));
    pgen[n] = p;
    pg_sh = p;
  }
  if (tid < 64) atomicAdd(&al_s[enc_in[b * L_ + tid]], aw_s[tid]);
  __syncthreads();
  if (tid < 96) {
    float a = al_s[tid] * (1.0f - pg_sh);
    unsigned short h = bf16rn(a);
    Ah[(size_t)n * KTOT + 512 + tid] = h;
    Al[(size_t)n * KTOT + 512 + tid] = bf16rn(a - bf16tof(h));
  }
}

// ---------------- fused output GEMM (split-bf16 3-term), COALESCED staging:
// out[n][v] = sum_k A[n][k]*B[v][k] + pg[n]*linb[v],  A = [pg*hs | (1-pg)*alpha], K=608.
// 128x128 tile, BK=32, 4 waves (2x2), wave tile 64x64 (4x4 16x16x32 MFMA tiles).
// R4 lesson: per-lane-row staging sprayed 64 cache lines per gload_lds (512
// line-requests/wave/K-step) -> TA request-rate bound at ~0.74 req/cyc/CU,
// MfmaUtil 12%. Fix: lanes 4j..4j+3 fetch the FOUR 16B k-granules of ONE row
// (one 64B line) -> 16 lines/instr, 4x fewer requests. The linear LDS write then
// gives row-major [row][32k]; the 2-bit XOR granule swizzle slot=g^((row>>1)&3)
// (applied to BOTH the global source and the hoisted read addrs - rule #21)
// breaks the 8-way stride-64B bank conflict down to 2-way (free).
__global__ __launch_bounds__(256) void k_out_gemm(
    const unsigned short* __restrict__ Ahg, const unsigned short* __restrict__ Alg,
    const unsigned short* __restrict__ Bhg, const unsigned short* __restrict__ Blg,
    const float* __restrict__ linb, const float* __restrict__ pgen,
    float* __restrict__ out) {
  __shared__ __align__(16) unsigned short SM[16384];   // Ah|Al|Bh|Bl, 4x8KB (128 rows x 32 k each)
  const int tid  = threadIdx.x;
  const int wave = tid >> 6, lane = tid & 63;
  const int l15  = lane & 15, l4 = lane >> 4;
  const int wm   = wave >> 1, wn = wave & 1;

  // XCD-chunked bijective swizzle over 8 x 235 = 1880 blocks
  int orig = blockIdx.x;
  int idw  = (orig & 7) * 235 + (orig >> 3);
  int mx   = idw & 7, ny = idw >> 3;
  const int m0 = mx * 128, n0 = ny * 128;

  // staging role: wave 0->Ah, 1->Al, 2->Bh, 3->Bl; 8 gload_lds each.
  // sub s covers rows s*16..s*16+15; lane l -> row r = s*16 + (l>>2),
  // slot = l&3, data granule g = slot ^ ((r>>1)&3) (XOR involution).
  const unsigned short* gmat = (wave == 0) ? Ahg : (wave == 1) ? Alg : (wave == 2) ? Bhg : Blg;
  const int rbase = (wave < 2) ? m0 : n0;
  const bool isB  = (wave >= 2);
  int soff[8];   // source offset within row-window (shorts): g*8
  int srow[8];
  #pragma unroll
  for (int sub = 0; sub < 8; ++sub) {
    int r = sub * 16 + (lane >> 2);
    int slot = lane & 3;
    int g = slot ^ ((r >> 1) & 3);
    int row = rbase + r;
    if (isB && row > V_ - 1) row = V_ - 1;
    srow[sub] = row;
    soff[sub] = g * 8;
  }

  // hoisted swizzled fragment read offsets (shorts, loop-invariant)
  int offA[4], offB[4];
  #pragma unroll
  for (int mi = 0; mi < 4; ++mi) {
    int ra = wm * 64 + mi * 16 + l15;
    offA[mi] = ra * 32 + (l4 ^ ((ra >> 1) & 3)) * 8;
  }
  #pragma unroll
  for (int ni = 0; ni < 4; ++ni) {
    int rb = wn * 64 + ni * 16 + l15;
    offB[ni] = rb * 32 + (l4 ^ ((rb >> 1) & 3)) * 8;
  }

  f32x4 acc[4][4] = {};

  for (int ks = 0; ks < KTOT / 32; ++ks) {
    const int k0 = ks * 32;
    #pragma unroll
    for (int sub = 0; sub < 8; ++sub) {
      const unsigned short* src = gmat + (size_t)srow[sub] * KTOT + k0 + soff[sub];
      gload_lds16(src, &SM[wave * 4096 + sub * 512]);
    }
    __syncthreads();   // compiler drains vmcnt(0) before s_barrier -> staged data visible
    s16x8 aH[4], aL[4], bH[4], bL[4];
    #pragma unroll
    for (int mi = 0; mi < 4; ++mi) {
      aH[mi] = *(const s16x8*)&SM[offA[mi]];
      aL[mi] = *(const s16x8*)&SM[4096 + offA[mi]];
    }
    #pragma unroll
    for (int ni = 0; ni < 4; ++ni) {
      bH[ni] = *(const s16x8*)&SM[8192 + offB[ni]];
      bL[ni] = *(const s16x8*)&SM[12288 + offB[ni]];
    }
    #pragma unroll
    for (int mi = 0; mi < 4; ++mi)
      #pragma unroll
      for (int ni = 0; ni < 4; ++ni) {
        acc[mi][ni] = __builtin_amdgcn_mfma_f32_16x16x32_bf16(aH[mi], bH[ni], acc[mi][ni], 0, 0, 0);
        acc[mi][ni] = __builtin_amdgcn_mfma_f32_16x16x32_bf16(aH[mi], bL[ni], acc[mi][ni], 0, 0, 0);
        acc[mi][ni] = __builtin_amdgcn_mfma_f32_16x16x32_bf16(aL[mi], bH[ni], acc[mi][ni], 0, 0, 0);
      }
    __syncthreads();
  }

  // epilogue: D frag col = lane&15, row = 4*(lane>>4)+reg  [m89-verified]
  float lbv[4]; int colv[4];
  #pragma unroll
  for (int ni = 0; ni < 4; ++ni) {
    int col = n0 + wn * 64 + ni * 16 + l15;
    colv[ni] = col;
    lbv[ni] = linb[col < V_ ? col : V_ - 1];
  }
  #pragma unroll
  for (int mi = 0; mi < 4; ++mi) {
    #pragma unroll
    for (int rr = 0; rr < 4; ++rr) {
      int row = m0 + wm * 64 + mi * 16 + l4 * 4 + rr;
      float pg = pgen[row];
      #pragma unroll
      for (int ni = 0; ni < 4; ++ni) {
        if (colv[ni] < V_)
          out[(size_t)row * V_ + colv[ni]] = acc[mi][ni][rr] + pg * lbv[ni];
      }
    }
  }
}

extern "C" void kernel_launch(void* const* d_in, const int* in_sizes, int n_in,
                              void* d_out, int out_size, void* d_ws, size_t ws_size,
                              hipStream_t stream) {
  const float* features = (const float*)d_in[0];
  const int*   captions = (const int*)d_in[1];
  const int*   enc_in   = (const int*)d_in[3];
  const float* enc_out  = (const float*)d_in[4];
  const float* embed_W  = (const float*)d_in[5];
  const float* W_ih     = (const float*)d_in[6];
  const float* W_hh     = (const float*)d_in[7];
  const float* b_ih     = (const float*)d_in[8];
  const float* b_hh     = (const float*)d_in[9];
  const float* linear_W = (const float*)d_in[10];
  const float* linear_b = (const float*)d_in[11];
  const float* attn_W   = (const float*)d_in[12];
  const float* attn_b   = (const float*)d_in[13];
  const float* pge_W    = (const float*)d_in[14];
  const float* pge_b    = (const float*)d_in[15];
  const float* pgd_W    = (const float*)d_in[16];
  const float* pgd_b    = (const float*)d_in[17];
  const float* conv     = (const float*)d_in[18];
  float* out = (float*)d_out;

  float* ws   = (float*)d_ws;
  float* X    = ws;                  // 262144 f
  float* Xg   = X    + 262144;       // 2097152 f
  float* hTb  = Xg   + 2097152;      // 32768 f
  float* hsb  = hTb  + 32768;        // 524288 f
  float* qws  = hsb  + 524288;       // 262144 f
  float* pgn  = qws  + 262144;       // 1024 f
  unsigned* bar = (unsigned*)(pgn + 1024);            // 1024 u32 reserved
  unsigned short* Ahg = (unsigned short*)(bar + 1024);
  unsigned short* Alg = Ahg + (size_t)NROWS * KTOT;   // 622592 each
  unsigned short* Bhg = Alg + (size_t)NROWS * KTOT;
  unsigned short* Blg = Bhg + (size_t)V_ * KTOT;      // 18240000 each

  hipMemsetAsync(bar, 0, 1024 * sizeof(unsigned), stream);
  // weight preprocessing (no deps on LSTM)
  k_split_lw<<<2048, 256, 0, stream>>>(linear_W, Bhg, Blg);
  k_convt   <<<469, 256, 0, stream>>>(conv, Bhg, Blg);

  k_gather <<<1024, 256, 0, stream>>>(features, captions, embed_W, X);
  k_gemm_bt<<<dim3(32, 16), 256, 0, stream>>>(X, W_ih, b_ih, b_hh, Xg, NROWS, G4_, EMB_);
  {
    const float* Xg_c = Xg;
    const float* Whh_c = W_hh;
    float* hTb_p = hTb;
    float* hsb_p = hsb;
    unsigned* bar_p = bar;
    void* args[] = { (void*)&Xg_c, (void*)&Whh_c, (void*)&hTb_p, (void*)&hsb_p,
                     (void*)&bar_p };
    hipLaunchCooperativeKernel((const void*)k_lstm_coop, dim3(256), dim3(256),
                               args, 0, stream);
  }
  k_gemm_bt<<<dim3(4, 16), 256, 0, stream>>>(hsb, attn_W, attn_b, nullptr, qws, NROWS, EMB_, HID_);
  k_attn   <<<1024, 256, 0, stream>>>(hsb, qws, enc_out, enc_in, pge_W, pge_b, pgd_W, pgd_b,
                                      Ahg, Alg, pgn);
  k_split_hs<<<512, 256, 0, stream>>>(hsb, pgn, Ahg, Alg);
  k_out_gemm<<<1880, 256, 0, stream>>>(Ahg, Alg, Bhg, Blg, linear_b, pgn, out);
}